// Round 7
// baseline (1258.649 us; speedup 1.0000x reference)
//
#include <hip/hip_runtime.h>
#include <hip/hip_bf16.h>
#include <stdint.h>

#define N_BATCH 4096
#define HID     1024
#define OBSLEN  20

#define BM  256   // batch rows per block
#define BK  64    // K per stage
// Block = 256x256 output (256 rows x [64 hcols x 4 gates] gate-interleaved).
// 4 waves (256 thr), wave-tile 128x128 (2M x 2N). 1 wave/SIMD, big-ILP design.

using short8 = __attribute__((ext_vector_type(8))) short;
using f32x4  = __attribute__((ext_vector_type(4))) float;

#define AS1 __attribute__((address_space(1)))
#define AS3 __attribute__((address_space(3)))

__device__ __forceinline__ float rcpf(float x) { return __builtin_amdgcn_rcpf(x); }
__device__ __forceinline__ float sigf(float x) { return rcpf(1.f + __expf(-x)); }
__device__ __forceinline__ float tanh_(float x) {
    float a = fminf(15.f, fmaxf(-15.f, x));
    float t = __expf(-2.f * a);
    return (1.f - t) * rcpf(1.f + t);
}
__device__ __forceinline__ unsigned short f2bf(float f) {
    __hip_bfloat16 b = __float2bfloat16(f);
    return *reinterpret_cast<unsigned short*>(&b);
}
__device__ __forceinline__ float bf2f(unsigned short u) {
    unsigned int x = ((unsigned int)u) << 16;
    return __uint_as_float(x);
}

// ---------------------------------------------------------------- prep ----
// hA = bf16(h0); cst = 0; Wg = bf16(W_hh) gate-interleaved row permutation:
// dest row R = by*256 + c' (by in [0,16)): gate g=(c'>>4)&3,
// hcol_local=((c'>>6)<<4)|(c'&15); source row = g*1024 + by*64 + hcol_local.
__global__ __launch_bounds__(256) void prep_kernel(
    const float4* __restrict__ Whh, const float4* __restrict__ h0,
    ushort4* __restrict__ Wg, ushort4* __restrict__ hb, float4* __restrict__ c, int n4)
{
    int i = blockIdx.x * 256 + threadIdx.x;
    if (i < n4) {
        float4 h = h0[i];
        hb[i] = make_ushort4(f2bf(h.x), f2bf(h.y), f2bf(h.z), f2bf(h.w));
        c[i] = make_float4(0.f, 0.f, 0.f, 0.f);
        int R  = i >> 8, k4 = i & 255;
        int by = R >> 8, cp = R & 255;
        int g  = (cp >> 4) & 3;
        int hl = ((cp >> 6) << 4) | (cp & 15);
        int orig = g * HID + by * 64 + hl;
        float4 w = Whh[orig * 256 + k4];
        Wg[i] = make_ushort4(f2bf(w.x), f2bf(w.y), f2bf(w.z), f2bf(w.w));
    }
}

// ---------------------------------------------------------- lstm step ----
// 4 waves, wave = 128x128 output: acc[8][8] (256 AGPR), frag double-buffer
// (af/bf current kk, af2/bf2 next kk) -> 32 ds_read_b128 + 128 MFMA per
// wave-tile (ratio 0.25; per CU 128 reads ~1540cyc < MFMA ~2480cyc).
// One raw s_barrier per K-tile (pre-barrier lgkmcnt(0) = cross-wave WAR
// safety); counted vmcnt(8) after barrier (A(kt+2) left in flight).
// LDS 128KB: A[2][256][64]bf16 @0, B[2][256][64]bf16 @65536.
// Content swizzle: element (row,kbyte) at row*128 + (kbyte ^ ((row&7)<<4)).
__global__ __launch_bounds__(256, 1) void lstm_step_kernel(
    const ushort* __restrict__ hin,   // [4096][1024] bf16 canonical
    const ushort* __restrict__ Wg,    // [4096][1024] bf16 permuted rows
    const float*  __restrict__ xt,    // [4096][2]
    const float*  __restrict__ Wih,   // [4096][2]
    const float*  __restrict__ bih,
    const float*  __restrict__ bhh,
    float*        __restrict__ cst,   // per-block [f][hb][tid] float4 layout
    ushort*       __restrict__ hout)  // [4096][1024] bf16 canonical
{
    __shared__ __align__(16) char lds[131072];
    const int tid  = threadIdx.x;
    const int lane = tid & 63, l15 = lane & 15, l4 = lane >> 4;
    const int wid  = tid >> 6, wr = wid >> 1, wcn = wid & 1;

    // XCD-aware remap (gridDim 16x16): same XCD keeps same W col-groups
    // across steps -> W slice L2-resident.
    const int L    = blockIdx.x + (int)gridDim.x * blockIdx.y;
    const int xcd  = L & 7, slot = L >> 3;
    const int xb   = slot & 15;
    const int yb   = (xcd << 1) | (slot >> 4);
    const int m0   = xb * BM;
    const int by   = yb;
    const int bid  = yb * 16 + xb;

    // ---- staging geometry (16B/thread/load; one round = 32 rows = 4KB) ----
    const int rowS = tid >> 3;                                  // 0..31
    const int offS = ((tid & 7) * 16) ^ ((rowS & 7) << 4);      // inverse-swizzled src byte
    const ushort* aS = hin + (size_t)(m0 + rowS) * HID + (offS >> 1);
    const ushort* bS = Wg  + (size_t)(by * 256 + rowS) * HID + (offS >> 1);
    char* aD = lds + tid * 16;
    char* bD = lds + 65536 + tid * 16;

    auto stA = [&](int s, int k0, int r) {
        __builtin_amdgcn_global_load_lds(
            (const AS1 void*)(aS + k0 + (size_t)r * 32 * HID),
            (AS3 void*)(aD + s * 32768 + r * 4096), 16, 0, 0);
    };
    auto stB = [&](int s, int k0, int r) {
        __builtin_amdgcn_global_load_lds(
            (const AS1 void*)(bS + k0 + (size_t)r * 32 * HID),
            (AS3 void*)(bD + s * 32768 + r * 4096), 16, 0, 0);
    };

    // ---- ds_read per-lane offsets ----
    const int swz = (l15 & 7) << 4;
    const int kb0 = (l4 * 16) ^ swz;                     // kk1 via ^64 (bit-disjoint)
    const int aRd = (wr * 128 + l15) * 128 + kb0;        // + s*32768 + f*2048
    const int bRd = 65536 + (wcn * 128 + l15) * 128 + kb0; // + s*32768 + n*2048

    f32x4 acc[8][8];
#pragma unroll
    for (int f = 0; f < 8; ++f)
#pragma unroll
        for (int n = 0; n < 8; ++n)
            acc[f][n] = (f32x4){0.f, 0.f, 0.f, 0.f};

    short8 af[8], bf[8], af2[8], bf2[8];

    // ---- prologue: stage T0 (A+B) + T1-A; vmcnt(8); barrier; read T0 kk0 ----
#pragma unroll
    for (int r = 0; r < 8; ++r) stA(0, 0, r);
#pragma unroll
    for (int r = 0; r < 8; ++r) stB(0, 0, r);
#pragma unroll
    for (int r = 0; r < 8; ++r) stA(1, 64, r);
    asm volatile("s_waitcnt vmcnt(8)" ::: "memory");   // T0 A+B landed; T1-A in flight
    __builtin_amdgcn_s_barrier();
#pragma unroll
    for (int f = 0; f < 8; ++f) af[f] = *(const short8*)(lds + aRd + f * 2048);
#pragma unroll
    for (int n = 0; n < 8; ++n) bf[n] = *(const short8*)(lds + bRd + n * 2048);

    const int NK = HID / BK; // 16
    for (int kt = 0; kt < NK; ++kt) {
        const int s = kt & 1, s1 = s ^ 1;
        const int aB = s * 32768 + aRd;
        const int bB = s * 32768 + bRd;

        // step 1: stage B(kt+1) -> slot s1
        if (kt < NK - 1) {
#pragma unroll
            for (int r = 0; r < 8; ++r) stB(s1, (kt + 1) * BK, r);
        }
        // step 2: read kk1 frags (slot s) into af2/bf2
#pragma unroll
        for (int f = 0; f < 8; ++f) af2[f] = *(const short8*)(lds + ((aB + f * 2048) ^ 64));
#pragma unroll
        for (int n = 0; n < 8; ++n) bf2[n] = *(const short8*)(lds + ((bB + n * 2048) ^ 64));
        // step 3: MFMA kk0 (64) — compiler interleaves with step-2 reads
#pragma unroll
        for (int f = 0; f < 8; ++f)
#pragma unroll
            for (int n = 0; n < 8; ++n)
                acc[f][n] = __builtin_amdgcn_mfma_f32_16x16x32_bf16(af[f], bf[n], acc[f][n], 0, 0, 0);

        // step 4: own reads done -> barrier (NO vmcnt drain; stages in flight)
        __builtin_amdgcn_sched_barrier(0);
        asm volatile("s_waitcnt lgkmcnt(0)" ::: "memory");
        __builtin_amdgcn_s_barrier();
        __builtin_amdgcn_sched_barrier(0);

        // step 5: stage A(kt+2) into freed A slot s
        if (kt < NK - 2) {
#pragma unroll
            for (int r = 0; r < 8; ++r) stA(s, (kt + 2) * BK, r);
        }
        // step 6: wait A(kt+1)+B(kt+1) landed (leave A(kt+2)); read kk0 of kt+1
        if (kt < NK - 1) {
            if (kt < NK - 2) asm volatile("s_waitcnt vmcnt(8)" ::: "memory");
            else             asm volatile("s_waitcnt vmcnt(0)" ::: "memory");
            __builtin_amdgcn_sched_barrier(0);
#pragma unroll
            for (int f = 0; f < 8; ++f) af[f] = *(const short8*)(lds + s1 * 32768 + aRd + f * 2048);
#pragma unroll
            for (int n = 0; n < 8; ++n) bf[n] = *(const short8*)(lds + s1 * 32768 + bRd + n * 2048);
        }
        // step 7: MFMA kk1 (64) on af2/bf2 — interleaves with step-6 reads
#pragma unroll
        for (int f = 0; f < 8; ++f)
#pragma unroll
            for (int n = 0; n < 8; ++n)
                acc[f][n] = __builtin_amdgcn_mfma_f32_16x16x32_bf16(af2[f], bf2[n], acc[f][n], 0, 0, 0);
    }

    // ---------------- epilogue: fused LSTM pointwise update ----------------
    // Block col c' = wcn*128 + n*16 + l15; gate = n&3; hb = n>>2;
    // hcol = by*64 + (wcn*2+hb)*16 + l15. Rows: m0 + wr*128 + f*16 + l4*4 + r.
    float4* c4 = (float4*)cst + (size_t)bid * 4096;   // [f][hb][tid] float4
    const float2* xt2 = (const float2*)xt;

    float wi0[2][4], wi1[2][4], bs_[2][4];
#pragma unroll
    for (int hb = 0; hb < 2; ++hb) {
        const int hcg = by * 64 + (wcn * 2 + hb) * 16 + l15;
#pragma unroll
        for (int g = 0; g < 4; ++g) {
            int j = g * HID + hcg;
            wi0[hb][g] = Wih[j * 2 + 0];
            wi1[hb][g] = Wih[j * 2 + 1];
            bs_[hb][g] = bih[j] + bhh[j];
        }
    }
#pragma unroll
    for (int f = 0; f < 8; ++f) {
#pragma unroll
        for (int hb = 0; hb < 2; ++hb) {
            const int hcg = by * 64 + (wcn * 2 + hb) * 16 + l15;
            float4 cv = c4[(f * 2 + hb) * 256 + tid];
#pragma unroll
            for (int r = 0; r < 4; ++r) {
                int nrow = m0 + wr * 128 + f * 16 + l4 * 4 + r;
                float2 x = xt2[nrow];
                float gi = acc[f][hb * 4 + 0][r] + x.x * wi0[hb][0] + x.y * wi1[hb][0] + bs_[hb][0];
                float gf = acc[f][hb * 4 + 1][r] + x.x * wi0[hb][1] + x.y * wi1[hb][1] + bs_[hb][1];
                float gg = acc[f][hb * 4 + 2][r] + x.x * wi0[hb][2] + x.y * wi1[hb][2] + bs_[hb][2];
                float go = acc[f][hb * 4 + 3][r] + x.x * wi0[hb][3] + x.y * wi1[hb][3] + bs_[hb][3];
                float iv = sigf(gi), fv = sigf(gf);
                float gv = tanh_(gg), ov = sigf(go);
                float cn = fv * cv[r] + iv * gv;
                cv[r] = cn;
                hout[(size_t)nrow * HID + hcg] = f2bf(ov * tanh_(cn));
            }
            c4[(f * 2 + hb) * 256 + tid] = cv;
        }
    }
}

// ----------------------------------------------------------- out proj ----
__global__ __launch_bounds__(256) void out_proj_kernel(
    const ushort* __restrict__ h, const float* __restrict__ Wout,
    const float* __restrict__ bout, float* __restrict__ outt)
{
    const int wid = threadIdx.x >> 6, lane = threadIdx.x & 63;
    const int row = blockIdx.x * 4 + wid;
    const ushort* hr = h + (size_t)row * HID + lane * 16;
    float a0 = 0.f, a1 = 0.f;
#pragma unroll
    for (int half = 0; half < 2; ++half) {
        short8 hv = *(const short8*)(hr + half * 8);
#pragma unroll
        for (int j = 0; j < 8; ++j) {
            int k = lane * 16 + half * 8 + j;
            float f = bf2f((unsigned short)hv[j]);
            a0 += f * Wout[k];
            a1 += f * Wout[HID + k];
        }
    }
#pragma unroll
    for (int off = 32; off > 0; off >>= 1) {
        a0 += __shfl_down(a0, off);
        a1 += __shfl_down(a1, off);
    }
    if (lane == 0) {
        outt[row * 2 + 0] = a0 + bout[0];
        outt[row * 2 + 1] = a1 + bout[1];
    }
}

// ------------------------------------------------------------- launch ----
extern "C" void kernel_launch(void* const* d_in, const int* in_sizes, int n_in,
                              void* d_out, int out_size, void* d_ws, size_t ws_size,
                              hipStream_t stream) {
    const float* obs  = (const float*)d_in[0];
    const float* h0   = (const float*)d_in[1];
    const float* Wih  = (const float*)d_in[2];
    const float* Whh  = (const float*)d_in[3];
    const float* bih  = (const float*)d_in[4];
    const float* bhh  = (const float*)d_in[5];
    const float* Wout = (const float*)d_in[6];
    const float* bout = (const float*)d_in[7];
    float* out = (float*)d_out;

    char* ws = (char*)d_ws;
    ushort* Wg = (ushort*)(ws);                 // 8 MB bf16 W_hh (permuted)
    ushort* hA = (ushort*)(ws + (8  << 20));    // 8 MB bf16 h ping
    ushort* hB = (ushort*)(ws + (16 << 20));    // 8 MB bf16 h pong
    float*  c  = (float* )(ws + (24 << 20));    // 16 MB fp32 c state (block-local)

    prep_kernel<<<4096, 256, 0, stream>>>((const float4*)Whh, (const float4*)h0,
                                          (ushort4*)Wg, (ushort4*)hA, (float4*)c,
                                          N_BATCH * HID / 4);

    ushort* hin = hA;
    ushort* hou = hB;
    for (int t = 0; t < OBSLEN; ++t) {
        const float* xt = obs + (size_t)(t == 0 ? 0 : (t - 1)) * N_BATCH * 2;
        lstm_step_kernel<<<dim3(N_BATCH / BM, (4 * HID) / 256), 256, 0, stream>>>(
            hin, Wg, xt, Wih, bih, bhh, c, hou);
        out_proj_kernel<<<N_BATCH / 4, 256, 0, stream>>>(
            hou, Wout, bout, out + (size_t)t * N_BATCH * 2);
        ushort* tmp = hin; hin = hou; hou = tmp;
    }
}